// Round 1
// baseline (168.441 us; speedup 1.0000x reference)
//
#include <hip/hip_runtime.h>

#define B_DIM 4096
#define I_DIM 1024
#define O_DIM 1024
#define ON_DIM 4096   // O * N fan-in columns

typedef _Float16 half8  __attribute__((ext_vector_type(8)));
typedef _Float16 half4_t __attribute__((ext_vector_type(4)));
typedef float    floatx4 __attribute__((ext_vector_type(4)));

// ---------------------------------------------------------------------------
// Kernel 1: row softmax of mapping_logits (O*N rows of I), output fp16 weights
// ---------------------------------------------------------------------------
__global__ __launch_bounds__(256)
void ltn_softmax_w(const float* __restrict__ logits, _Float16* __restrict__ wh) {
  __shared__ float redmax[4];
  __shared__ float redsum[4];
  const int row  = blockIdx.x;
  const int t    = threadIdx.x;
  const int lane = t & 63;
  const int wv   = t >> 6;
  const float4 v = ((const float4*)(logits + (size_t)row * I_DIM))[t];
  float m = fmaxf(fmaxf(v.x, v.y), fmaxf(v.z, v.w));
#pragma unroll
  for (int off = 32; off > 0; off >>= 1) m = fmaxf(m, __shfl_down(m, off));
  if (lane == 0) redmax[wv] = m;
  __syncthreads();
  m = fmaxf(fmaxf(redmax[0], redmax[1]), fmaxf(redmax[2], redmax[3]));
  const float e0 = __expf(v.x - m), e1 = __expf(v.y - m);
  const float e2 = __expf(v.z - m), e3 = __expf(v.w - m);
  float s = (e0 + e1) + (e2 + e3);
#pragma unroll
  for (int off = 32; off > 0; off >>= 1) s += __shfl_down(s, off);
  if (lane == 0) redsum[wv] = s;
  __syncthreads();
  s = (redsum[0] + redsum[1]) + (redsum[2] + redsum[3]);
  const float inv = 1.0f / s;
  half4_t h;
  h[0] = (_Float16)(e0 * inv); h[1] = (_Float16)(e1 * inv);
  h[2] = (_Float16)(e2 * inv); h[3] = (_Float16)(e3 * inv);
  ((half4_t*)(wh + (size_t)row * I_DIM))[t] = h;
}

// ---------------------------------------------------------------------------
// Kernel 2: x (B,I) fp32 -> fp16
// ---------------------------------------------------------------------------
__global__ __launch_bounds__(256)
void ltn_convert_x(const float* __restrict__ x, _Float16* __restrict__ xh) {
  const int idx  = blockIdx.x * 256 + threadIdx.x;
  const float4 v = ((const float4*)x)[idx];
  half4_t h;
  h[0] = (_Float16)v.x; h[1] = (_Float16)v.y;
  h[2] = (_Float16)v.z; h[3] = (_Float16)v.w;
  ((half4_t*)xh)[idx] = h;
}

// ---------------------------------------------------------------------------
// Kernel 3: fused GEMM (selected = x @ w^T) + sigmoid + 16-corner LUT interp.
// 128x128 block tile, 4 waves (2x2), each wave 64x64 = 4x4 MFMA 16x16x32 f16.
// LDS k-blocked layout [kb][m][8] so global_load_lds width=16 lands contiguous
// (wave-uniform base + lane*16) and fragments read with ds_read_b128.
// ---------------------------------------------------------------------------
__global__ __launch_bounds__(256)
void ltn_gemm_lut(const _Float16* __restrict__ xh,   // [B][I]
                  const _Float16* __restrict__ wh,   // [ON][I]
                  const float* __restrict__ lut,     // [O][16]
                  float* __restrict__ out) {         // [B][O]
  __shared__ _Float16 As[4][128][8];   // 8 KB: kb (k-block of 8), m, j
  __shared__ _Float16 Bs[4][128][8];   // 8 KB

  const int tid  = threadIdx.x;
  const int lane = tid & 63;
  const int wv   = tid >> 6;     // wave 0..3
  const int wr   = wv >> 1;      // wave row (0..1)  -> 64 rows
  const int wc   = wv & 1;       // wave col (0..1)  -> 64 on-cols
  const int bm0  = blockIdx.x * 128;
  const int bn0  = blockIdx.y * 128;

  const int fm = lane & 15;      // m/n within a 16-tile
  const int kq = lane >> 4;      // quad -> k-block index (k = kq*8 + j)

  floatx4 acc[4][4];
#pragma unroll
  for (int i = 0; i < 4; i++)
#pragma unroll
    for (int j = 0; j < 4; j++) acc[i][j] = (floatx4)0.0f;

  for (int k0 = 0; k0 < I_DIM; k0 += 32) {
    // ---- stage: 512 chunks of 16B per matrix; 2 wave-instructions per wave
#pragma unroll
    for (int s = 0; s < 2; s++) {
      const int ci0 = (wv * 2 + s) * 64;          // wave-uniform
      const int ci  = ci0 + lane;
      const int m   = ci & 127;
      const int kb  = ci >> 7;
      const _Float16* gA = xh + (size_t)(bm0 + m) * I_DIM + k0 + kb * 8;
      const _Float16* gB = wh + (size_t)(bn0 + m) * I_DIM + k0 + kb * 8;
      __builtin_amdgcn_global_load_lds(
          (const __attribute__((address_space(1))) void*)gA,
          (__attribute__((address_space(3))) void*)(&As[0][0][0] + ci0 * 8),
          16, 0, 0);
      __builtin_amdgcn_global_load_lds(
          (const __attribute__((address_space(1))) void*)gB,
          (__attribute__((address_space(3))) void*)(&Bs[0][0][0] + ci0 * 8),
          16, 0, 0);
    }
    __syncthreads();

    // ---- fragments + 16 MFMAs
    half8 af[4], bf[4];
#pragma unroll
    for (int t = 0; t < 4; t++) {
      af[t] = *(const half8*)&As[kq][wr * 64 + t * 16 + fm][0];
      bf[t] = *(const half8*)&Bs[kq][wc * 64 + t * 16 + fm][0];
    }
#pragma unroll
    for (int mt = 0; mt < 4; mt++)
#pragma unroll
      for (int nt = 0; nt < 4; nt++)
        acc[mt][nt] = __builtin_amdgcn_mfma_f32_16x16x32_f16(
            af[mt], bf[nt], acc[mt][nt], 0, 0, 0);
    __syncthreads();
  }

  // ---- fused epilogue: sigmoid -> gather 4 fan-in values -> LUT contraction
  // C/D layout: col = lane&15, row = (lane>>4)*4 + reg. The 4 n-values of one
  // o live in 4 consecutive lanes (same row, cols o*4..o*4+3).
#pragma unroll
  for (int nt = 0; nt < 4; nt++) {
    const int o = (bn0 + wc * 64 + nt * 16 + (lane & 15)) >> 2;
    const float4* lt4 = (const float4*)(lut + (size_t)o * 16);
    const float4 L0 = lt4[0], L1 = lt4[1], L2 = lt4[2], L3 = lt4[3];
#pragma unroll
    for (int mt = 0; mt < 4; mt++) {
#pragma unroll
      for (int r = 0; r < 4; r++) {
        const float v  = acc[mt][nt][r];
        const float sv = 1.0f / (1.0f + __expf(-v));
        const float s1 = __shfl_down(sv, 1);
        const float s2 = __shfl_down(sv, 2);
        const float s3 = __shfl_down(sv, 3);
        if ((lane & 3) == 0) {
          const float s0 = sv;
          // contract corner bit 3 (stride 8) with s3
          const float a0 = L0.x + (L2.x - L0.x) * s3;
          const float a1 = L0.y + (L2.y - L0.y) * s3;
          const float a2 = L0.z + (L2.z - L0.z) * s3;
          const float a3 = L0.w + (L2.w - L0.w) * s3;
          const float a4 = L1.x + (L3.x - L1.x) * s3;
          const float a5 = L1.y + (L3.y - L1.y) * s3;
          const float a6 = L1.z + (L3.z - L1.z) * s3;
          const float a7 = L1.w + (L3.w - L1.w) * s3;
          // bit 2 (stride 4) with s2
          const float b0 = a0 + (a4 - a0) * s2;
          const float b1 = a1 + (a5 - a1) * s2;
          const float b2 = a2 + (a6 - a2) * s2;
          const float b3 = a3 + (a7 - a3) * s2;
          // bit 1 (stride 2) with s1
          const float c0 = b0 + (b2 - b0) * s1;
          const float c1 = b1 + (b3 - b1) * s1;
          // bit 0 with s0
          const float res = c0 + (c1 - c0) * s0;
          const int row = bm0 + wr * 64 + mt * 16 + (lane >> 4) * 4 + r;
          out[(size_t)row * O_DIM + o] = res;
        }
      }
    }
  }
}

// ---------------------------------------------------------------------------
extern "C" void kernel_launch(void* const* d_in, const int* in_sizes, int n_in,
                              void* d_out, int out_size, void* d_ws, size_t ws_size,
                              hipStream_t stream) {
  const float* x      = (const float*)d_in[0];  // (B, I)
  const float* logits = (const float*)d_in[1];  // (O, N, I)
  const float* lut    = (const float*)d_in[2];  // (O, 16)
  float* out          = (float*)d_out;          // (B, O)

  _Float16* wh = (_Float16*)d_ws;                                  // 8 MB
  _Float16* xh = (_Float16*)d_ws + (size_t)ON_DIM * I_DIM;         // 8 MB

  ltn_softmax_w<<<ON_DIM, 256, 0, stream>>>(logits, wh);
  ltn_convert_x<<<(B_DIM * I_DIM / 4) / 256, 256, 0, stream>>>(x, xh);
  dim3 grid(B_DIM / 128, ON_DIM / 128);
  ltn_gemm_lut<<<grid, 256, 0, stream>>>(xh, wh, lut, out);
}

// Round 2
// 167.310 us; speedup vs baseline: 1.0068x; 1.0068x over previous
//
#include <hip/hip_runtime.h>

#define B_DIM 4096
#define I_DIM 1024
#define O_DIM 1024
#define ON_DIM 4096   // O * N fan-in columns

typedef _Float16 half8  __attribute__((ext_vector_type(8)));
typedef _Float16 half4_t __attribute__((ext_vector_type(4)));
typedef float    floatx4 __attribute__((ext_vector_type(4)));

// ---------------------------------------------------------------------------
// Kernel 1 (fused prep):
//  blocks [0,1024):   softmax of mapping_logits rows -> fp16 weights.
//                     One wave per row (4 rows/block), barrier-free,
//                     __shfl_xor butterfly reductions.
//  blocks [1024,2048): x fp32 -> fp16 convert, 4 float4 per thread.
// ---------------------------------------------------------------------------
__global__ __launch_bounds__(256)
void ltn_prep(const float* __restrict__ logits, const float* __restrict__ x,
              _Float16* __restrict__ wh, _Float16* __restrict__ xh) {
  const int t = threadIdx.x, lane = t & 63, wv = t >> 6;
  if (blockIdx.x < 1024) {
    const int row = blockIdx.x * 4 + wv;
    const float4* src = (const float4*)(logits + (size_t)row * I_DIM);
    float4 v[4];
#pragma unroll
    for (int j = 0; j < 4; j++) v[j] = src[j * 64 + lane];
    float m = -1e30f;
#pragma unroll
    for (int j = 0; j < 4; j++)
      m = fmaxf(m, fmaxf(fmaxf(v[j].x, v[j].y), fmaxf(v[j].z, v[j].w)));
#pragma unroll
    for (int off = 1; off < 64; off <<= 1) m = fmaxf(m, __shfl_xor(m, off));
    float e[16];
    float s = 0.0f;
#pragma unroll
    for (int j = 0; j < 4; j++) {
      e[4 * j + 0] = __expf(v[j].x - m);
      e[4 * j + 1] = __expf(v[j].y - m);
      e[4 * j + 2] = __expf(v[j].z - m);
      e[4 * j + 3] = __expf(v[j].w - m);
      s += (e[4 * j + 0] + e[4 * j + 1]) + (e[4 * j + 2] + e[4 * j + 3]);
    }
#pragma unroll
    for (int off = 1; off < 64; off <<= 1) s += __shfl_xor(s, off);
    const float inv = 1.0f / s;
    half4_t* dst = (half4_t*)(wh + (size_t)row * I_DIM);
#pragma unroll
    for (int j = 0; j < 4; j++) {
      half4_t h;
      h[0] = (_Float16)(e[4 * j + 0] * inv);
      h[1] = (_Float16)(e[4 * j + 1] * inv);
      h[2] = (_Float16)(e[4 * j + 2] * inv);
      h[3] = (_Float16)(e[4 * j + 3] * inv);
      dst[j * 64 + lane] = h;
    }
  } else {
    const int cidx = blockIdx.x - 1024;
    const float4* src = (const float4*)x;
    half4_t* dst = (half4_t*)xh;
#pragma unroll
    for (int j = 0; j < 4; j++) {
      const int idx = cidx * 1024 + j * 256 + t;
      const float4 v = src[idx];
      half4_t h;
      h[0] = (_Float16)v.x; h[1] = (_Float16)v.y;
      h[2] = (_Float16)v.z; h[3] = (_Float16)v.w;
      dst[idx] = h;
    }
  }
}

// ---------------------------------------------------------------------------
// Kernel 2: fused GEMM (selected = x @ w^T) + sigmoid + 16-corner LUT interp.
// 128x128 block tile, BK=64 (halves barrier-drain count vs BK=32; LDS 32 KB
// keeps 3 blocks/CU — reg-limited, not LDS-limited). 4 waves (2x2), each wave
// 64x64 = 4x4 MFMA 16x16x32 f16, 2 k-steps per staged tile.
// LDS k-blocked layout [kb][m][8]: global_load_lds width=16 lands contiguous
// (wave-uniform base + lane*16) and fragments read with ds_read_b128.
// ---------------------------------------------------------------------------
__global__ __launch_bounds__(256)
void ltn_gemm_lut(const _Float16* __restrict__ xh,   // [B][I]
                  const _Float16* __restrict__ wh,   // [ON][I]
                  const float* __restrict__ lut,     // [O][16]
                  float* __restrict__ out) {         // [B][O]
  __shared__ _Float16 As[8][128][8];   // 16 KB: kb (k-block of 8), m, j
  __shared__ _Float16 Bs[8][128][8];   // 16 KB

  const int tid  = threadIdx.x;
  const int lane = tid & 63;
  const int wv   = tid >> 6;     // wave 0..3
  const int wr   = wv >> 1;      // wave row (0..1)  -> 64 rows
  const int wc   = wv & 1;       // wave col (0..1)  -> 64 on-cols
  const int bm0  = blockIdx.x * 128;
  const int bn0  = blockIdx.y * 128;

  const int fm = lane & 15;      // m/n within a 16-tile
  const int kq = lane >> 4;      // quad -> k-block index (k = kq*8 + j)

  floatx4 acc[4][4];
#pragma unroll
  for (int i = 0; i < 4; i++)
#pragma unroll
    for (int j = 0; j < 4; j++) acc[i][j] = (floatx4)0.0f;

  for (int k0 = 0; k0 < I_DIM; k0 += 64) {
    // ---- stage 16 KB per matrix: 1024 chunks of 16 B; 4 per wave per matrix
#pragma unroll
    for (int s = 0; s < 4; s++) {
      const int ci0 = (wv * 4 + s) * 64;          // wave-uniform
      const int ci  = ci0 + lane;
      const int m   = ci & 127;
      const int kb  = ci >> 7;
      const _Float16* gA = xh + (size_t)(bm0 + m) * I_DIM + k0 + kb * 8;
      const _Float16* gB = wh + (size_t)(bn0 + m) * I_DIM + k0 + kb * 8;
      __builtin_amdgcn_global_load_lds(
          (const __attribute__((address_space(1))) void*)gA,
          (__attribute__((address_space(3))) void*)(&As[0][0][0] + ci0 * 8),
          16, 0, 0);
      __builtin_amdgcn_global_load_lds(
          (const __attribute__((address_space(1))) void*)gB,
          (__attribute__((address_space(3))) void*)(&Bs[0][0][0] + ci0 * 8),
          16, 0, 0);
    }
    __syncthreads();

    // ---- 2 k-steps of 32; 16 MFMAs each
#pragma unroll
    for (int t = 0; t < 2; t++) {
      half8 af[4], bf[4];
#pragma unroll
      for (int f = 0; f < 4; f++) {
        af[f] = *(const half8*)&As[t * 4 + kq][wr * 64 + f * 16 + fm][0];
        bf[f] = *(const half8*)&Bs[t * 4 + kq][wc * 64 + f * 16 + fm][0];
      }
#pragma unroll
      for (int mt = 0; mt < 4; mt++)
#pragma unroll
        for (int nt = 0; nt < 4; nt++)
          acc[mt][nt] = __builtin_amdgcn_mfma_f32_16x16x32_f16(
              af[mt], bf[nt], acc[mt][nt], 0, 0, 0);
    }
    __syncthreads();
  }

  // ---- fused epilogue: sigmoid -> gather 4 fan-in values -> LUT contraction
  // C/D layout: col = lane&15, row = (lane>>4)*4 + reg. The 4 n-values of one
  // o live in 4 consecutive lanes (same row, cols o*4..o*4+3).
#pragma unroll
  for (int nt = 0; nt < 4; nt++) {
    const int o = (bn0 + wc * 64 + nt * 16 + (lane & 15)) >> 2;
    const float4* lt4 = (const float4*)(lut + (size_t)o * 16);
    const float4 L0 = lt4[0], L1 = lt4[1], L2 = lt4[2], L3 = lt4[3];
#pragma unroll
    for (int mt = 0; mt < 4; mt++) {
#pragma unroll
      for (int r = 0; r < 4; r++) {
        const float v  = acc[mt][nt][r];
        const float sv = 1.0f / (1.0f + __expf(-v));
        const float s1 = __shfl_down(sv, 1);
        const float s2 = __shfl_down(sv, 2);
        const float s3 = __shfl_down(sv, 3);
        if ((lane & 3) == 0) {
          const float s0 = sv;
          // contract corner bit 3 (stride 8) with s3
          const float a0 = L0.x + (L2.x - L0.x) * s3;
          const float a1 = L0.y + (L2.y - L0.y) * s3;
          const float a2 = L0.z + (L2.z - L0.z) * s3;
          const float a3 = L0.w + (L2.w - L0.w) * s3;
          const float a4 = L1.x + (L3.x - L1.x) * s3;
          const float a5 = L1.y + (L3.y - L1.y) * s3;
          const float a6 = L1.z + (L3.z - L1.z) * s3;
          const float a7 = L1.w + (L3.w - L1.w) * s3;
          // bit 2 (stride 4) with s2
          const float b0 = a0 + (a4 - a0) * s2;
          const float b1 = a1 + (a5 - a1) * s2;
          const float b2 = a2 + (a6 - a2) * s2;
          const float b3 = a3 + (a7 - a3) * s2;
          // bit 1 (stride 2) with s1
          const float c0 = b0 + (b2 - b0) * s1;
          const float c1 = b1 + (b3 - b1) * s1;
          // bit 0 with s0
          const float res = c0 + (c1 - c0) * s0;
          const int row = bm0 + wr * 64 + mt * 16 + (lane >> 4) * 4 + r;
          out[(size_t)row * O_DIM + o] = res;
        }
      }
    }
  }
}

// ---------------------------------------------------------------------------
extern "C" void kernel_launch(void* const* d_in, const int* in_sizes, int n_in,
                              void* d_out, int out_size, void* d_ws, size_t ws_size,
                              hipStream_t stream) {
  const float* x      = (const float*)d_in[0];  // (B, I)
  const float* logits = (const float*)d_in[1];  // (O, N, I)
  const float* lut    = (const float*)d_in[2];  // (O, 16)
  float* out          = (float*)d_out;          // (B, O)

  _Float16* wh = (_Float16*)d_ws;                                  // 8 MB
  _Float16* xh = (_Float16*)d_ws + (size_t)ON_DIM * I_DIM;         // 8 MB

  ltn_prep<<<2048, 256, 0, stream>>>(logits, x, wh, xh);
  dim3 grid(B_DIM / 128, ON_DIM / 128);
  ltn_gemm_lut<<<grid, 256, 0, stream>>>(xh, wh, lut, out);
}